// Round 1
// baseline (387.998 us; speedup 1.0000x reference)
//
#include <hip/hip_runtime.h>
#include <math.h>

#define BATCH 16
#define CH 320

// ---------------- workspace layout (in floats) ----------------
// pooled p3 templates: 3 * B*C*64
static constexpr size_t WS_POOL3 = 0;
static constexpr size_t WS_POOL4 = 3u * BATCH * CH * 64;            // 983040
static constexpr size_t WS_A     = WS_POOL4 + 3u * BATCH * CH * 64; // 1966080, 3*48 floats
static constexpr size_t WS_TN    = WS_A + 144;                      // 1966224, 3 * B*C*64
static constexpr size_t WS_INV3  = WS_TN + 3u * BATCH * CH * 64;    // 2949264, B*64*64
static constexpr size_t WS_INV4  = WS_INV3 + BATCH * 64 * 64;       // 3014800, B*32*32
static constexpr size_t WS_INV5  = WS_INV4 + BATCH * 32 * 32;       // 3031184, B*16*16

// ---------------- 1) pool templates to 8x8 (means) ----------------
template <int HW, int KK>
__global__ void pool_kernel(const float* __restrict__ a0, const float* __restrict__ a1,
                            const float* __restrict__ a2, float* __restrict__ dst) {
    int idx = blockIdx.x * blockDim.x + threadIdx.x;
    constexpr int NPL = BATCH * CH * 64;
    if (idx >= 3 * NPL) return;
    int tmpl = idx / NPL;
    int r = idx % NPL;
    const float* src = (tmpl == 0) ? a0 : ((tmpl == 1) ? a1 : a2);
    int bc = r >> 6;
    int pos = r & 63;
    int oh = pos >> 3, ow = pos & 7;
    const float* base = src + (size_t)bc * HW * HW;
    float s = 0.0f;
    if constexpr (KK == 4) {
#pragma unroll
        for (int i = 0; i < 4; ++i) {
            float4 v = *(const float4*)(base + (oh * 4 + i) * HW + ow * 4);
            s += v.x + v.y + v.z + v.w;
        }
    } else {
#pragma unroll
        for (int i = 0; i < 2; ++i) {
            float2 v = *(const float2*)(base + (oh * 2 + i) * HW + ow * 2);
            s += v.x + v.y;
        }
    }
    dst[idx] = s * (1.0f / (KK * KK));
}

// ---------------- 2) fusion weights: mean -> MLP -> softmax ----------------
__global__ void weights_kernel(const float* __restrict__ p0, const float* __restrict__ p1,
                               const float* __restrict__ p2,
                               const float* __restrict__ w1, const float* __restrict__ b1,
                               const float* __restrict__ w2, const float* __restrict__ b2,
                               float* __restrict__ a_out) {
    __shared__ float m[3][CH];
    __shared__ float hv[3][80];
    __shared__ float sc[3];
    int b = blockIdx.x;
    int t = threadIdx.x;
    const float* ps[3] = {p0, p1, p2};
#pragma unroll
    for (int i = 0; i < 3; ++i) {
        for (int c = t; c < CH; c += 256) {
            const float* q = ps[i] + ((size_t)b * CH + c) * 64;
            float s = 0.0f;
#pragma unroll 8
            for (int k = 0; k < 64; ++k) s += q[k];
            m[i][c] = s * (1.0f / 64.0f);
        }
    }
    __syncthreads();
    for (int j = t; j < 240; j += 256) {
        int i = j / 80, jj = j % 80;
        float acc = b1[jj];
        for (int c = 0; c < CH; ++c) acc = fmaf(m[i][c], w1[c * 80 + jj], acc);
        hv[i][jj] = fmaxf(acc, 0.0f) * w2[jj];
    }
    __syncthreads();
    if (t < 3) {
        float s = b2[0];
#pragma unroll 8
        for (int jj = 0; jj < 80; ++jj) s += hv[t][jj];
        sc[t] = s;
    }
    __syncthreads();
    if (t == 0) {
        float mx = fmaxf(sc[0], fmaxf(sc[1], sc[2]));
        float e0 = expf(sc[0] - mx), e1 = expf(sc[1] - mx), e2 = expf(sc[2] - mx);
        float inv = 1.0f / (e0 + e1 + e2);
        a_out[b * 3 + 0] = e0 * inv;
        a_out[b * 3 + 1] = e1 * inv;
        a_out[b * 3 + 2] = e2 * inv;
    }
}

// ---------------- 3) fused pooled template + L2 norm over C ----------------
__global__ void fuse_norm_kernel(const float* __restrict__ p0, const float* __restrict__ p1,
                                 const float* __restrict__ p2, const float* __restrict__ a_in,
                                 float* __restrict__ tn) {
    __shared__ float ssp[256];
    __shared__ float sinv[64];
    int b = blockIdx.x;
    int t = threadIdx.x;
    float a0 = a_in[b * 3 + 0], a1 = a_in[b * 3 + 1], a2 = a_in[b * 3 + 2];
    size_t base = (size_t)b * CH * 64;
    float ss = 0.0f;
    for (int idx = t; idx < CH * 64; idx += 256) {
        float v = a0 * p0[base + idx] + a1 * p1[base + idx] + a2 * p2[base + idx];
        ss = fmaf(v, v, ss);
    }
    ssp[t] = ss;   // pos = t & 63 is constant per thread (stride 256 keeps idx%64 fixed)
    __syncthreads();
    if (t < 64) {
        float s = ssp[t] + ssp[t + 64] + ssp[t + 128] + ssp[t + 192];
        sinv[t] = 1.0f / fmaxf(sqrtf(s), 1e-12f);
    }
    __syncthreads();
    for (int idx = t; idx < CH * 64; idx += 256) {
        float v = a0 * p0[base + idx] + a1 * p1[base + idx] + a2 * p2[base + idx];
        tn[base + idx] = v * sinv[idx & 63];
    }
}

// ---------------- 4) per-position inverse L2 norm of search ----------------
template <int H>
__global__ void inv_norm_kernel(const float* __restrict__ s, float* __restrict__ inv) {
    int idx = blockIdx.x * blockDim.x + threadIdx.x;
    constexpr int HW = H * H;
    if (idx >= BATCH * HW) return;
    int b = idx / HW;
    int hw = idx % HW;
    const float* q = s + (size_t)b * CH * HW + hw;
    float ss = 0.0f;
#pragma unroll 4
    for (int c = 0; c < CH; ++c) {
        float v = q[(size_t)c * HW];
        ss = fmaf(v, v, ss);
    }
    inv[idx] = 1.0f / fmaxf(sqrtf(ss), 1e-12f);
}

// ---------------- 5) correlation ----------------
// grid.x = B * NSTRIP * CSPLIT, block = TR*TC threads, each owns RB x CB outputs.
template <int H, int OH, int TR, int TC, int RB, int CB, int CSPLIT, int CC>
__global__ void corr_kernel(const float* __restrict__ sraw, const float* __restrict__ invn,
                            const float* __restrict__ tn, float* __restrict__ out) {
    constexpr int NT = TR * TC;
    constexpr int SR = TR * RB;                     // output rows per strip
    constexpr int NSTRIP = (OH + SR - 1) / SR;
    constexpr int LR = (SR + 7 < H) ? (SR + 7) : H; // loaded search rows
    constexpr int LSTR = ((H + 4 + 3) / 4) * 4;     // padded LDS row stride (words, 16B-aligned)
    constexpr int CPB = CH / CSPLIT;                // channels per block

    __shared__ float sT[CPB * 64];
    __shared__ float sInv[LR * H];
    __shared__ float sS[CC * LR * LSTR + 16];       // +16 slack for read overrun of masked lanes

    int bid = blockIdx.x;
    int cs = bid % CSPLIT;
    int strip = (bid / CSPLIT) % NSTRIP;
    int b = bid / (CSPLIT * NSTRIP);
    int row0 = strip * SR;
    int c0 = cs * CPB;
    int t = threadIdx.x;
    int loadR = (H - row0 < LR) ? (H - row0) : LR;

    {   // template chunk (contiguous, coalesced)
        const float* tb = tn + ((size_t)b * CH + c0) * 64;
        for (int i = t; i < CPB * 64; i += NT) sT[i] = tb[i];
    }
    {   // inv-norm tile for this strip (reused for all channels)
        const float* ib = invn + ((size_t)b * H + row0) * H;
        for (int i = t; i < loadR * H; i += NT) sInv[i] = ib[i];
    }

    float acc[RB][CB];
#pragma unroll
    for (int r = 0; r < RB; ++r)
#pragma unroll
        for (int cb = 0; cb < CB; ++cb) acc[r][cb] = 0.0f;

    int tr = t / TC, tc = t % TC;
    int ohb = tr * RB, owb = tc * CB;

    for (int cc0 = 0; cc0 < CPB; cc0 += CC) {
        __syncthreads();  // covers preloads on iter 0, protects sS reuse afterwards
        const float* sb = sraw + (((size_t)b * CH + c0 + cc0) * H + row0) * H;
#pragma unroll
        for (int ch = 0; ch < CC; ++ch) {
            for (int i = t; i < loadR * H; i += NT) {
                int rr = i / H;          // H is a power of two -> shifts
                int cw = i % H;
                sS[ch * (LR * LSTR) + rr * LSTR + cw] = sb[(size_t)ch * H * H + i] * sInv[i];
            }
        }
        __syncthreads();
#pragma unroll
        for (int ch = 0; ch < CC; ++ch) {
            const float* Sb = sS + ch * (LR * LSTR);
            const float* Tb = sT + (cc0 + ch) * 64;
#pragma unroll
            for (int sr = 0; sr < RB + 7; ++sr) {
                int lrow = ohb + sr;
                lrow = (lrow < LR - 1) ? lrow : (LR - 1);   // clamp: garbage only feeds masked outputs
                const float4* rp = (const float4*)(Sb + lrow * LSTR + owb);
                float4 s0 = rp[0], s1 = rp[1], s2 = rp[2];
                float seg[12] = {s0.x, s0.y, s0.z, s0.w, s1.x, s1.y, s1.z, s1.w,
                                 s2.x, s2.y, s2.z, s2.w};
#pragma unroll
                for (int r = 0; r < RB; ++r) {
                    if (sr - r >= 0 && sr - r < 8) {        // compile-time after unroll
                        const int kh = sr - r;
                        const float4* tp = (const float4*)(Tb + kh * 8);
                        float4 t0 = tp[0], t1 = tp[1];
                        float tv[8] = {t0.x, t0.y, t0.z, t0.w, t1.x, t1.y, t1.z, t1.w};
#pragma unroll
                        for (int kw = 0; kw < 8; ++kw)
#pragma unroll
                            for (int cb = 0; cb < CB; ++cb)
                                acc[r][cb] = fmaf(tv[kw], seg[kw + cb], acc[r][cb]);
                    }
                }
            }
        }
    }

#pragma unroll
    for (int r = 0; r < RB; ++r) {
        int oh = row0 + ohb + r;
        if (oh < OH) {
#pragma unroll
            for (int cb = 0; cb < CB; ++cb) {
                int ow = owb + cb;
                if (ow < OH) {
                    __hip_atomic_fetch_add(out + ((size_t)b * OH + oh) * OH + ow, acc[r][cb],
                                           __ATOMIC_RELAXED, __HIP_MEMORY_SCOPE_AGENT);
                }
            }
        }
    }
}

extern "C" void kernel_launch(void* const* d_in, const int* in_sizes, int n_in,
                              void* d_out, int out_size, void* d_ws, size_t ws_size,
                              hipStream_t stream) {
    const float* t0p3 = (const float*)d_in[0];
    const float* t0p4 = (const float*)d_in[1];
    const float* t0p5 = (const float*)d_in[2];
    const float* t1p3 = (const float*)d_in[3];
    const float* t1p4 = (const float*)d_in[4];
    const float* t1p5 = (const float*)d_in[5];
    const float* t2p3 = (const float*)d_in[6];
    const float* t2p4 = (const float*)d_in[7];
    const float* t2p5 = (const float*)d_in[8];
    const float* sp3  = (const float*)d_in[9];
    const float* sp4  = (const float*)d_in[10];
    const float* sp5  = (const float*)d_in[11];
    const float* f3w1 = (const float*)d_in[12];
    const float* f3b1 = (const float*)d_in[13];
    const float* f3w2 = (const float*)d_in[14];
    const float* f3b2 = (const float*)d_in[15];
    const float* f4w1 = (const float*)d_in[16];
    const float* f4b1 = (const float*)d_in[17];
    const float* f4w2 = (const float*)d_in[18];
    const float* f4b2 = (const float*)d_in[19];
    const float* f5w1 = (const float*)d_in[20];
    const float* f5b1 = (const float*)d_in[21];
    const float* f5w2 = (const float*)d_in[22];
    const float* f5b2 = (const float*)d_in[23];

    float* ws = (float*)d_ws;
    float* out = (float*)d_out;
    constexpr size_t PLSZ = (size_t)BATCH * CH * 64;  // 327680

    // out is accumulated by atomics and replays are not re-poisoned -> zero each call
    hipMemsetAsync(d_out, 0, (size_t)out_size * sizeof(float), stream);

    // 1) pool templates (p5 is already 8x8; used in place)
    pool_kernel<32, 4><<<3840, 256, 0, stream>>>(t0p3, t1p3, t2p3, ws + WS_POOL3);
    pool_kernel<16, 2><<<3840, 256, 0, stream>>>(t0p4, t1p4, t2p4, ws + WS_POOL4);

    // 2) fusion weights per level
    weights_kernel<<<16, 256, 0, stream>>>(ws + WS_POOL3, ws + WS_POOL3 + PLSZ,
                                           ws + WS_POOL3 + 2 * PLSZ,
                                           f3w1, f3b1, f3w2, f3b2, ws + WS_A);
    weights_kernel<<<16, 256, 0, stream>>>(ws + WS_POOL4, ws + WS_POOL4 + PLSZ,
                                           ws + WS_POOL4 + 2 * PLSZ,
                                           f4w1, f4b1, f4w2, f4b2, ws + WS_A + 48);
    weights_kernel<<<16, 256, 0, stream>>>(t0p5, t1p5, t2p5,
                                           f5w1, f5b1, f5w2, f5b2, ws + WS_A + 96);

    // 3) fused + L2-normalized 8x8 templates
    fuse_norm_kernel<<<16, 256, 0, stream>>>(ws + WS_POOL3, ws + WS_POOL3 + PLSZ,
                                             ws + WS_POOL3 + 2 * PLSZ, ws + WS_A, ws + WS_TN);
    fuse_norm_kernel<<<16, 256, 0, stream>>>(ws + WS_POOL4, ws + WS_POOL4 + PLSZ,
                                             ws + WS_POOL4 + 2 * PLSZ, ws + WS_A + 48,
                                             ws + WS_TN + PLSZ);
    fuse_norm_kernel<<<16, 256, 0, stream>>>(t0p5, t1p5, t2p5, ws + WS_A + 96,
                                             ws + WS_TN + 2 * PLSZ);

    // 4) per-position inverse norms of searches
    inv_norm_kernel<64><<<256, 256, 0, stream>>>(sp3, ws + WS_INV3);
    inv_norm_kernel<32><<<64, 256, 0, stream>>>(sp4, ws + WS_INV4);
    inv_norm_kernel<16><<<16, 256, 0, stream>>>(sp5, ws + WS_INV5);

    // 5) correlation  (grid = B * NSTRIP * CSPLIT)
    corr_kernel<64, 57, 16, 16, 2, 4, 16, 2><<<512, 256, 0, stream>>>(
        sp3, ws + WS_INV3, ws + WS_TN, out);
    corr_kernel<32, 25, 32, 8, 1, 4, 32, 2><<<512, 256, 0, stream>>>(
        sp4, ws + WS_INV4, ws + WS_TN + PLSZ, out + 51984);
    corr_kernel<16, 9, 16, 4, 1, 4, 32, 2><<<512, 64, 0, stream>>>(
        sp5, ws + WS_INV5, ws + WS_TN + 2 * PLSZ, out + 61984);
}

// Round 2
// 217.838 us; speedup vs baseline: 1.7811x; 1.7811x over previous
//
#include <hip/hip_runtime.h>
#include <math.h>

#define BATCH 16
#define CH 320

// ---------------- workspace layout (in floats) ----------------
static constexpr size_t PLSZ     = (size_t)BATCH * CH * 64;          // 327680
static constexpr size_t WS_POOL3 = 0;                                // 3*PLSZ
static constexpr size_t WS_POOL4 = WS_POOL3 + 3 * PLSZ;              // 983040
static constexpr size_t WS_MEANS = WS_POOL4 + 3 * PLSZ;              // 1966080, 3 lvl * 3 tmpl * 16 * 320
static constexpr size_t WS_A     = WS_MEANS + 3 * 3 * BATCH * CH;    // 2012160, 3*48
static constexpr size_t WS_TN    = WS_A + 144;                       // 2012304, 3*PLSZ (fused, then scaled in place)
static constexpr size_t WS_PART  = WS_TN + 3 * PLSZ;                 // 2995344, 3*16*80*64
static constexpr size_t WS_SINV  = WS_PART + 3 * BATCH * 80 * 64;    // 3241104, 3*1024
static constexpr size_t WS_INV3  = WS_SINV + 3 * 1024;               // 3244176, 16*4096
static constexpr size_t WS_INV4  = WS_INV3 + BATCH * 64 * 64;        // 16*1024
static constexpr size_t WS_INV5  = WS_INV4 + BATCH * 32 * 32;        // 16*256

// ---------------- 1) pool templates to 8x8 + fused per-(tmpl,b,c) mean ----------------
template <int HW, int KK>
__global__ void pool_kernel(const float* __restrict__ a0, const float* __restrict__ a1,
                            const float* __restrict__ a2, float* __restrict__ dst,
                            float* __restrict__ means) {
    int idx = blockIdx.x * blockDim.x + threadIdx.x;   // grid covers exactly 3*PLSZ
    constexpr int NPL = BATCH * CH * 64;
    int tmpl = idx / NPL;
    int r = idx % NPL;
    const float* src = (tmpl == 0) ? a0 : ((tmpl == 1) ? a1 : a2);
    int bc = r >> 6;
    int pos = r & 63;
    int oh = pos >> 3, ow = pos & 7;
    const float* base = src + (size_t)bc * HW * HW;
    float s = 0.0f;
    if constexpr (KK == 4) {
#pragma unroll
        for (int i = 0; i < 4; ++i) {
            float4 v = *(const float4*)(base + (oh * 4 + i) * HW + ow * 4);
            s += v.x + v.y + v.z + v.w;
        }
    } else {
#pragma unroll
        for (int i = 0; i < 2; ++i) {
            float2 v = *(const float2*)(base + (oh * 2 + i) * HW + ow * 2);
            s += v.x + v.y;
        }
    }
    s *= (1.0f / (KK * KK));
    dst[idx] = s;
    // wave holds all 64 positions of one (tmpl,b,c): reduce -> mean
    float m = s;
#pragma unroll
    for (int o = 32; o; o >>= 1) m += __shfl_xor(m, o);
    if ((threadIdx.x & 63) == 0) means[tmpl * (BATCH * CH) + bc] = m * (1.0f / 64.0f);
}

// mean over 64 elems for p5 (already 8x8): one wave per (tmpl,b,c) row
__global__ void mean64_kernel(const float* __restrict__ a0, const float* __restrict__ a1,
                              const float* __restrict__ a2, float* __restrict__ means) {
    int w = (blockIdx.x * 256 + threadIdx.x) >> 6;   // row 0..15359
    int lane = threadIdx.x & 63;
    constexpr int NR = BATCH * CH;
    int tmpl = w / NR;
    int rem = w % NR;
    const float* src = (tmpl == 0) ? a0 : ((tmpl == 1) ? a1 : a2);
    float v = src[(size_t)rem * 64 + lane];
#pragma unroll
    for (int o = 32; o; o >>= 1) v += __shfl_xor(v, o);
    if (lane == 0) means[w] = v * (1.0f / 64.0f);
}

// ---------------- 2) fusion weights: means -> MLP -> softmax (all levels, 48 blocks) ----------------
__global__ void weights_kernel(const float* __restrict__ means,
                               const float* w13, const float* b13, const float* w23, const float* b23,
                               const float* w14, const float* b14, const float* w24, const float* b24,
                               const float* w15, const float* b15, const float* w25, const float* b25,
                               float* __restrict__ a_out) {
    __shared__ float m[3 * CH];
    __shared__ float hv[240];
    __shared__ float sc[3];
    int lvl = blockIdx.x / BATCH;
    int b = blockIdx.x % BATCH;
    int t = threadIdx.x;
    const float* w1 = (lvl == 0) ? w13 : ((lvl == 1) ? w14 : w15);
    const float* b1 = (lvl == 0) ? b13 : ((lvl == 1) ? b14 : b15);
    const float* w2 = (lvl == 0) ? w23 : ((lvl == 1) ? w24 : w25);
    const float* b2 = (lvl == 0) ? b23 : ((lvl == 1) ? b24 : b25);
    const float* mb = means + lvl * (3 * BATCH * CH);
    for (int j = t; j < 3 * CH; j += 256) {
        int i = j / CH, c = j % CH;
        m[j] = mb[i * (BATCH * CH) + b * CH + c];
    }
    __syncthreads();
    if (t < 240) {
        int i = t / 80, jj = t % 80;
        float acc = b1[jj];
#pragma unroll 4
        for (int c = 0; c < CH; ++c) acc = fmaf(m[i * CH + c], w1[c * 80 + jj], acc);
        hv[t] = fmaxf(acc, 0.0f) * w2[jj];
    }
    __syncthreads();
    if (t < 3) {
        float s = b2[0];
#pragma unroll 8
        for (int jj = 0; jj < 80; ++jj) s += hv[t * 80 + jj];
        sc[t] = s;
    }
    __syncthreads();
    if (t == 0) {
        float mx = fmaxf(sc[0], fmaxf(sc[1], sc[2]));
        float e0 = expf(sc[0] - mx), e1 = expf(sc[1] - mx), e2 = expf(sc[2] - mx);
        float inv = 1.0f / (e0 + e1 + e2);
        float* ao = a_out + lvl * 48 + b * 3;
        ao[0] = e0 * inv; ao[1] = e1 * inv; ao[2] = e2 * inv;
    }
}

// ---------------- 3a) fuse templates + per-block partial sum of squares ----------------
__global__ void fuse_kernel(const float* __restrict__ p30, const float* __restrict__ p31, const float* __restrict__ p32,
                            const float* __restrict__ p40, const float* __restrict__ p41, const float* __restrict__ p42,
                            const float* __restrict__ p50, const float* __restrict__ p51, const float* __restrict__ p52,
                            const float* __restrict__ aw, float* __restrict__ tf,
                            float* __restrict__ partial) {
    __shared__ float red[256];
    int lvl = blockIdx.x / 1280;
    int r = blockIdx.x % 1280;
    int t = threadIdx.x;
    const float* p0 = (lvl == 0) ? p30 : ((lvl == 1) ? p40 : p50);
    const float* p1 = (lvl == 0) ? p31 : ((lvl == 1) ? p41 : p51);
    const float* p2 = (lvl == 0) ? p32 : ((lvl == 1) ? p42 : p52);
    int idx = r * 256 + t;            // within-level flat index
    int b = r / 80;                   // 80 blocks per batch
    int j = r % 80;
    const float* ab = aw + lvl * 48 + b * 3;
    float a0 = ab[0], a1 = ab[1], a2 = ab[2];
    float v = a0 * p0[idx] + a1 * p1[idx] + a2 * p2[idx];
    tf[(size_t)lvl * PLSZ + idx] = v;
    red[t] = v * v;
    __syncthreads();
    if (t < 64) {
        float s = red[t] + red[t + 64] + red[t + 128] + red[t + 192];
        partial[((size_t)(lvl * BATCH + b) * 80 + j) * 64 + t] = s;
    }
}

// ---------------- 3b) finalize template inverse norms (3072 cells) ----------------
__global__ void tnorm_finalize_kernel(const float* __restrict__ partial, float* __restrict__ sinv) {
    int cell = blockIdx.x * 256 + threadIdx.x;   // < 3072
    int lvl = cell >> 10;
    int rem = cell & 1023;
    int b = rem >> 6;
    int pos = cell & 63;
    const float* p = partial + ((size_t)(lvl * BATCH + b) * 80) * 64 + pos;
    float s = 0.0f;
#pragma unroll 8
    for (int j = 0; j < 80; ++j) s += p[j * 64];
    sinv[cell] = 1.0f / fmaxf(sqrtf(s), 1e-12f);
}

// ---------------- 3c) scale fused templates in place ----------------
__global__ void tscale_kernel(float* __restrict__ tf, const float* __restrict__ sinv) {
    int i4 = blockIdx.x * 256 + threadIdx.x;     // < 245760 float4s
    int lvl = i4 / 81920;
    int rem = i4 % 81920;
    int b = rem / 5120;
    float4 v = ((float4*)tf)[i4];
    float4 sv = ((const float4*)sinv)[lvl * 256 + b * 16 + (i4 & 15)];
    v.x *= sv.x; v.y *= sv.y; v.z *= sv.z; v.w *= sv.w;
    ((float4*)tf)[i4] = v;
}

// ---------------- 4) per-position inverse L2 norm of search (C split inside block) ----------------
template <int H>
__global__ void inv_norm_kernel(const float* __restrict__ s, float* __restrict__ inv) {
    constexpr int HW = H * H;
    constexpr int TILES = HW / 64;
    __shared__ float red[256];
    int blk = blockIdx.x;
    int t = threadIdx.x;
    int b = blk / TILES;
    int tile = blk % TILES;
    int hw = tile * 64 + (t & 63);
    int q = t >> 6;                                // C quarter
    const float* p = s + ((size_t)b * CH + q * 80) * HW + hw;
    float ss = 0.0f;
#pragma unroll 8
    for (int c = 0; c < 80; ++c) {
        float v = p[(size_t)c * HW];
        ss = fmaf(v, v, ss);
    }
    red[t] = ss;
    __syncthreads();
    if (t < 64) {
        float sum = red[t] + red[t + 64] + red[t + 128] + red[t + 192];
        inv[(size_t)b * HW + tile * 64 + t] = 1.0f / fmaxf(sqrtf(sum), 1e-12f);
    }
}

// ---------------- 5) correlation ----------------
template <int H, int OH, int TR, int TC, int RB, int CB, int CSPLIT, int CC>
__global__ void corr_kernel(const float* __restrict__ sraw, const float* __restrict__ invn,
                            const float* __restrict__ tn, float* __restrict__ out) {
    constexpr int NT = TR * TC;
    constexpr int SR = TR * RB;
    constexpr int NSTRIP = (OH + SR - 1) / SR;
    constexpr int LR = (SR + 7 < H) ? (SR + 7) : H;
    constexpr int LSTR = ((H + 4 + 3) / 4) * 4;    // padded row stride (words)
    constexpr int CPB = CH / CSPLIT;
    constexpr int W4 = H / 4;

    __shared__ float sT[CPB * 64];
    __shared__ float4 sInv4[LR * W4];
    __shared__ float sS[CC * LR * LSTR + 16];

    int bid = blockIdx.x;
    int cs = bid % CSPLIT;
    int strip = (bid / CSPLIT) % NSTRIP;
    int b = bid / (CSPLIT * NSTRIP);
    int row0 = strip * SR;
    int c0 = cs * CPB;
    int t = threadIdx.x;
    int loadR = (H - row0 < LR) ? (H - row0) : LR;

    {   // template chunk
        const float4* tb = (const float4*)(tn + ((size_t)b * CH + c0) * 64);
        for (int i = t; i < CPB * 16; i += NT) ((float4*)sT)[i] = tb[i];
    }
    {   // inv-norm tile for this strip
        const float4* ib = (const float4*)(invn + ((size_t)b * H + row0) * H);
        for (int i = t; i < loadR * W4; i += NT) sInv4[i] = ib[i];
    }

    float acc[RB][CB];
#pragma unroll
    for (int r = 0; r < RB; ++r)
#pragma unroll
        for (int cb = 0; cb < CB; ++cb) acc[r][cb] = 0.0f;

    int tr = t / TC, tc = t % TC;
    int ohb = tr * RB, owb = tc * CB;

    for (int cc0 = 0; cc0 < CPB; cc0 += CC) {
        __syncthreads();  // covers preloads on iter 0, protects sS reuse afterwards
        const float4* sb = (const float4*)(sraw + (((size_t)b * CH + c0 + cc0) * H + row0) * H);
#pragma unroll
        for (int ch = 0; ch < CC; ++ch) {
            const float4* src = sb + (size_t)ch * (H * H / 4);
            for (int i4 = t; i4 < loadR * W4; i4 += NT) {
                int rr = i4 / W4;                  // W4 pow2 -> shift
                int c4 = i4 % W4;
                float4 v = src[rr * W4 + c4];
                float4 n = sInv4[i4];
                v.x *= n.x; v.y *= n.y; v.z *= n.z; v.w *= n.w;
                *(float4*)&sS[ch * (LR * LSTR) + rr * LSTR + c4 * 4] = v;
            }
        }
        __syncthreads();
#pragma unroll
        for (int ch = 0; ch < CC; ++ch) {
            const float* Sb = sS + ch * (LR * LSTR);
            const float* Tb = sT + (cc0 + ch) * 64;
#pragma unroll
            for (int sr = 0; sr < RB + 7; ++sr) {
                int lrow = ohb + sr;
                lrow = (lrow < LR - 1) ? lrow : (LR - 1);   // clamp: garbage only feeds masked outputs
                const float4* rp = (const float4*)(Sb + lrow * LSTR + owb);
                float4 s0 = rp[0], s1 = rp[1], s2 = rp[2];
                float seg[12] = {s0.x, s0.y, s0.z, s0.w, s1.x, s1.y, s1.z, s1.w,
                                 s2.x, s2.y, s2.z, s2.w};
#pragma unroll
                for (int r = 0; r < RB; ++r) {
                    if (sr - r >= 0 && sr - r < 8) {        // compile-time after unroll
                        const int kh = sr - r;
                        const float4* tp = (const float4*)(Tb + kh * 8);
                        float4 t0 = tp[0], t1 = tp[1];
                        float tv[8] = {t0.x, t0.y, t0.z, t0.w, t1.x, t1.y, t1.z, t1.w};
#pragma unroll
                        for (int kw = 0; kw < 8; ++kw)
#pragma unroll
                            for (int cb = 0; cb < CB; ++cb)
                                acc[r][cb] = fmaf(tv[kw], seg[kw + cb], acc[r][cb]);
                    }
                }
            }
        }
    }

#pragma unroll
    for (int r = 0; r < RB; ++r) {
        int oh = row0 + ohb + r;
        if (oh < OH) {
#pragma unroll
            for (int cb = 0; cb < CB; ++cb) {
                int ow = owb + cb;
                if (ow < OH) {
                    __hip_atomic_fetch_add(out + ((size_t)b * OH + oh) * OH + ow, acc[r][cb],
                                           __ATOMIC_RELAXED, __HIP_MEMORY_SCOPE_AGENT);
                }
            }
        }
    }
}

extern "C" void kernel_launch(void* const* d_in, const int* in_sizes, int n_in,
                              void* d_out, int out_size, void* d_ws, size_t ws_size,
                              hipStream_t stream) {
    const float* t0p3 = (const float*)d_in[0];
    const float* t0p4 = (const float*)d_in[1];
    const float* t0p5 = (const float*)d_in[2];
    const float* t1p3 = (const float*)d_in[3];
    const float* t1p4 = (const float*)d_in[4];
    const float* t1p5 = (const float*)d_in[5];
    const float* t2p3 = (const float*)d_in[6];
    const float* t2p4 = (const float*)d_in[7];
    const float* t2p5 = (const float*)d_in[8];
    const float* sp3  = (const float*)d_in[9];
    const float* sp4  = (const float*)d_in[10];
    const float* sp5  = (const float*)d_in[11];
    const float* f3w1 = (const float*)d_in[12];
    const float* f3b1 = (const float*)d_in[13];
    const float* f3w2 = (const float*)d_in[14];
    const float* f3b2 = (const float*)d_in[15];
    const float* f4w1 = (const float*)d_in[16];
    const float* f4b1 = (const float*)d_in[17];
    const float* f4w2 = (const float*)d_in[18];
    const float* f4b2 = (const float*)d_in[19];
    const float* f5w1 = (const float*)d_in[20];
    const float* f5b1 = (const float*)d_in[21];
    const float* f5w2 = (const float*)d_in[22];
    const float* f5b2 = (const float*)d_in[23];

    float* ws = (float*)d_ws;
    float* out = (float*)d_out;

    hipMemsetAsync(d_out, 0, (size_t)out_size * sizeof(float), stream);

    // 1) pool templates (+ fused means); mean-only for p5
    pool_kernel<32, 4><<<3840, 256, 0, stream>>>(t0p3, t1p3, t2p3, ws + WS_POOL3, ws + WS_MEANS);
    pool_kernel<16, 2><<<3840, 256, 0, stream>>>(t0p4, t1p4, t2p4, ws + WS_POOL4,
                                                 ws + WS_MEANS + 3 * BATCH * CH);
    mean64_kernel<<<3840, 256, 0, stream>>>(t0p5, t1p5, t2p5, ws + WS_MEANS + 6 * BATCH * CH);

    // 2) fusion weights, all levels
    weights_kernel<<<48, 256, 0, stream>>>(ws + WS_MEANS,
                                           f3w1, f3b1, f3w2, f3b2,
                                           f4w1, f4b1, f4w2, f4b2,
                                           f5w1, f5b1, f5w2, f5b2, ws + WS_A);

    // 3) fuse + normalize templates (full-grid, deterministic partials)
    fuse_kernel<<<3840, 256, 0, stream>>>(ws + WS_POOL3, ws + WS_POOL3 + PLSZ, ws + WS_POOL3 + 2 * PLSZ,
                                          ws + WS_POOL4, ws + WS_POOL4 + PLSZ, ws + WS_POOL4 + 2 * PLSZ,
                                          t0p5, t1p5, t2p5,
                                          ws + WS_A, ws + WS_TN, ws + WS_PART);
    tnorm_finalize_kernel<<<12, 256, 0, stream>>>(ws + WS_PART, ws + WS_SINV);
    tscale_kernel<<<960, 256, 0, stream>>>(ws + WS_TN, ws + WS_SINV);

    // 4) per-position inverse norms of searches
    inv_norm_kernel<64><<<1024, 256, 0, stream>>>(sp3, ws + WS_INV3);
    inv_norm_kernel<32><<<256, 256, 0, stream>>>(sp4, ws + WS_INV4);
    inv_norm_kernel<16><<<64, 256, 0, stream>>>(sp5, ws + WS_INV5);

    // 5) correlation
    corr_kernel<64, 57, 8, 16, 2, 4, 32, 2><<<2048, 128, 0, stream>>>(
        sp3, ws + WS_INV3, ws + WS_TN, out);
    corr_kernel<32, 25, 16, 8, 2, 4, 80, 2><<<1280, 128, 0, stream>>>(
        sp4, ws + WS_INV4, ws + WS_TN + PLSZ, out + 51984);
    corr_kernel<16, 9, 16, 4, 1, 4, 80, 2><<<1280, 64, 0, stream>>>(
        sp5, ws + WS_INV5, ws + WS_TN + 2 * PLSZ, out + 61984);
}

// Round 3
// 97.063 us; speedup vs baseline: 3.9974x; 2.2443x over previous
//
#include <hip/hip_runtime.h>
#include <math.h>

#define BATCH 16
#define CH 320

typedef __attribute__((ext_vector_type(8))) short bf16x8;
typedef __attribute__((ext_vector_type(4))) short shortx4;
typedef __attribute__((ext_vector_type(4))) float f32x4;

// ---------------- workspace layout (floats) ----------------
static constexpr size_t PLSZ     = (size_t)BATCH * CH * 64;      // 327680
static constexpr size_t WS_POOL3 = 0;                            // 3*PLSZ (U overlaps later)
static constexpr size_t WS_POOL4 = 3 * PLSZ;
static constexpr size_t WS_TF    = 6 * PLSZ;
static constexpr size_t WS_MEANS = 9 * PLSZ;                     // 2949120
static constexpr size_t WS_AW    = WS_MEANS + 9 * BATCH * CH;    // +46080
static constexpr size_t WS_PART  = WS_AW + 144;
static constexpr size_t WS_ABF   = WS_PART + 3 * BATCH * 80 * 64; // bf16 A, 983040 shorts
// U (bf16 shorts, overlapping POOL3/POOL4/TF which are dead by GEMM time)
static constexpr size_t UB3 = 0;
static constexpr size_t UB4 = (size_t)BATCH * 64 * 4096;         // 4194304
static constexpr size_t UB5 = UB4 + (size_t)BATCH * 64 * 1024;   // 5242880 (end 5505024 shorts < 9*PLSZ/… fits)

__device__ __forceinline__ float bf2f(unsigned short u) {
    union { unsigned int i; float f; } x; x.i = ((unsigned int)u) << 16; return x.f;
}
__device__ __forceinline__ unsigned short f2bf(float f) {
    union { float f; unsigned int i; } x; x.f = f;
    return (unsigned short)((x.i + 0x7FFFu + ((x.i >> 16) & 1u)) >> 16);
}

// ---------------- 1) fused pool(p3)+pool(p4)+mean(p5), all with per-(tmpl,b,c) means ----------------
template <int HW, int KK>
__device__ __forceinline__ void pool_body(int idx, const float* __restrict__ a0,
                                          const float* __restrict__ a1, const float* __restrict__ a2,
                                          float* __restrict__ dst, float* __restrict__ means, int lane) {
    constexpr int NPL = BATCH * CH * 64;
    int tmpl = idx / NPL;
    int r = idx % NPL;
    const float* src = (tmpl == 0) ? a0 : ((tmpl == 1) ? a1 : a2);
    int bc = r >> 6;
    int pos = r & 63;
    int oh = pos >> 3, ow = pos & 7;
    const float* base = src + (size_t)bc * HW * HW;
    float s = 0.0f;
    if constexpr (KK == 4) {
#pragma unroll
        for (int i = 0; i < 4; ++i) {
            float4 v = *(const float4*)(base + (oh * 4 + i) * HW + ow * 4);
            s += v.x + v.y + v.z + v.w;
        }
    } else {
#pragma unroll
        for (int i = 0; i < 2; ++i) {
            float2 v = *(const float2*)(base + (oh * 2 + i) * HW + ow * 2);
            s += v.x + v.y;
        }
    }
    s *= (1.0f / (KK * KK));
    dst[idx] = s;
    float m = s;                       // wave holds all 64 positions of one (tmpl,b,c)
#pragma unroll
    for (int o = 32; o; o >>= 1) m += __shfl_xor(m, o);
    if (lane == 0) means[tmpl * (BATCH * CH) + bc] = m * (1.0f / 64.0f);
}

__global__ __launch_bounds__(256) void prep_kernel(
    const float* __restrict__ t0p3, const float* __restrict__ t1p3, const float* __restrict__ t2p3,
    const float* __restrict__ t0p4, const float* __restrict__ t1p4, const float* __restrict__ t2p4,
    const float* __restrict__ t0p5, const float* __restrict__ t1p5, const float* __restrict__ t2p5,
    float* __restrict__ pool3, float* __restrict__ pool4, float* __restrict__ means) {
    int bid = blockIdx.x, t = threadIdx.x, lane = t & 63;
    if (bid < 3840) {
        pool_body<32, 4>(bid * 256 + t, t0p3, t1p3, t2p3, pool3, means, lane);
    } else if (bid < 7680) {
        pool_body<16, 2>((bid - 3840) * 256 + t, t0p4, t1p4, t2p4, pool4, means + 3 * BATCH * CH, lane);
    } else {
        int w = ((bid - 7680) * 256 + t) >> 6;     // row 0..15359
        constexpr int NR = BATCH * CH;
        int tmpl = w / NR, rem = w % NR;
        const float* src = (tmpl == 0) ? t0p5 : ((tmpl == 1) ? t1p5 : t2p5);
        float v = src[(size_t)rem * 64 + lane];
#pragma unroll
        for (int o = 32; o; o >>= 1) v += __shfl_xor(v, o);
        if (lane == 0) means[6 * BATCH * CH + w] = v * (1.0f / 64.0f);
    }
}

// ---------------- 2) fusion weights: means -> MLP -> softmax (48 blocks) ----------------
__global__ __launch_bounds__(256) void weights_kernel(const float* __restrict__ means,
        const float* w13, const float* b13, const float* w23, const float* b23,
        const float* w14, const float* b14, const float* w24, const float* b24,
        const float* w15, const float* b15, const float* w25, const float* b25,
        float* __restrict__ a_out) {
    __shared__ float m[3 * CH];
    __shared__ float hv[240];
    __shared__ float sc[3];
    int lvl = blockIdx.x / BATCH;
    int b = blockIdx.x % BATCH;
    int t = threadIdx.x;
    const float* w1 = (lvl == 0) ? w13 : ((lvl == 1) ? w14 : w15);
    const float* b1 = (lvl == 0) ? b13 : ((lvl == 1) ? b14 : b15);
    const float* w2 = (lvl == 0) ? w23 : ((lvl == 1) ? w24 : w25);
    const float* b2 = (lvl == 0) ? b23 : ((lvl == 1) ? b24 : b25);
    const float* mb = means + lvl * (3 * BATCH * CH);
    for (int j = t; j < 3 * CH; j += 256) {
        int i = j / CH, c = j % CH;
        m[j] = mb[i * (BATCH * CH) + b * CH + c];
    }
    __syncthreads();
    if (t < 240) {
        int i = t / 80, jj = t % 80;
        float acc = b1[jj];
#pragma unroll 4
        for (int c = 0; c < CH; ++c) acc = fmaf(m[i * CH + c], w1[c * 80 + jj], acc);
        hv[t] = fmaxf(acc, 0.0f) * w2[jj];
    }
    __syncthreads();
    if (t < 3) {
        float s = b2[0];
#pragma unroll 8
        for (int jj = 0; jj < 80; ++jj) s += hv[t * 80 + jj];
        sc[t] = s;
    }
    __syncthreads();
    if (t == 0) {
        float mx = fmaxf(sc[0], fmaxf(sc[1], sc[2]));
        float e0 = expf(sc[0] - mx), e1 = expf(sc[1] - mx), e2 = expf(sc[2] - mx);
        float inv = 1.0f / (e0 + e1 + e2);
        float* ao = a_out + lvl * 48 + b * 3;
        ao[0] = e0 * inv; ao[1] = e1 * inv; ao[2] = e2 * inv;
    }
}

// ---------------- 3a) fuse templates + per-block partial sum of squares ----------------
__global__ __launch_bounds__(256) void fuse_kernel(
        const float* __restrict__ p30, const float* __restrict__ p31, const float* __restrict__ p32,
        const float* __restrict__ p40, const float* __restrict__ p41, const float* __restrict__ p42,
        const float* __restrict__ p50, const float* __restrict__ p51, const float* __restrict__ p52,
        const float* __restrict__ aw, float* __restrict__ tf, float* __restrict__ partial) {
    __shared__ float red[256];
    int lvl = blockIdx.x / 1280;
    int r = blockIdx.x % 1280;
    int t = threadIdx.x;
    const float* p0 = (lvl == 0) ? p30 : ((lvl == 1) ? p40 : p50);
    const float* p1 = (lvl == 0) ? p31 : ((lvl == 1) ? p41 : p51);
    const float* p2 = (lvl == 0) ? p32 : ((lvl == 1) ? p42 : p52);
    int idx = r * 256 + t;
    int b = r / 80;
    int j = r % 80;
    const float* ab = aw + lvl * 48 + b * 3;
    float a0 = ab[0], a1 = ab[1], a2 = ab[2];
    float v = a0 * p0[idx] + a1 * p1[idx] + a2 * p2[idx];
    tf[(size_t)lvl * PLSZ + idx] = v;
    red[t] = v * v;
    __syncthreads();
    if (t < 64) {
        float s = red[t] + red[t + 64] + red[t + 128] + red[t + 192];
        partial[((size_t)(lvl * BATCH + b) * 80 + j) * 64 + t] = s;
    }
}

// ---------------- 3b) finalize sinv + transpose + scale -> bf16 A [lvl][b][p][c] ----------------
__global__ __launch_bounds__(256) void atrans_kernel(const float* __restrict__ tf,
        const float* __restrict__ part, short* __restrict__ abf) {
    __shared__ float lds[64 * 68];
    __shared__ float red2[4 * 64];
    __shared__ float sv[64];
    int lvl = blockIdx.x >> 4;
    int b = blockIdx.x & 15;
    int t = threadIdx.x;
    {
        const float* p = part + ((size_t)(lvl * BATCH + b) * 80) * 64 + (t & 63);
        int jg = t >> 6;
        float s = 0.0f;
        for (int j = jg * 20; j < jg * 20 + 20; ++j) s += p[j * 64];
        red2[jg * 64 + (t & 63)] = s;
    }
    __syncthreads();
    if (t < 64) {
        float s = red2[t] + red2[64 + t] + red2[128 + t] + red2[192 + t];
        sv[t] = 1.0f / fmaxf(sqrtf(s), 1e-12f);
    }
    __syncthreads();
    const float* tb = tf + (size_t)lvl * PLSZ + (size_t)b * (CH * 64);
    short* ab = abf + ((size_t)(lvl * BATCH + b) * 64) * 320;
    for (int c0 = 0; c0 < 320; c0 += 64) {
        __syncthreads();
#pragma unroll
        for (int i = 0; i < 4; ++i) {
            int c = (t >> 4) + 16 * i;
            int p4 = (t & 15) * 4;
            *(float4*)(lds + c * 68 + p4) = *(const float4*)(tb + (size_t)(c0 + c) * 64 + p4);
        }
        __syncthreads();
        int p = t >> 2;
        int cs = (t & 3) * 16;
        float s_p = sv[p];
        bf16x8 o0, o1;
#pragma unroll
        for (int u = 0; u < 8; ++u) o0[u] = (short)f2bf(lds[(cs + u) * 68 + p] * s_p);
#pragma unroll
        for (int u = 0; u < 8; ++u) o1[u] = (short)f2bf(lds[(cs + 8 + u) * 68 + p] * s_p);
        *(bf16x8*)(ab + (size_t)p * 320 + c0 + cs) = o0;
        *(bf16x8*)(ab + (size_t)p * 320 + c0 + cs + 8) = o1;
    }
}

// ---------------- 4) MFMA GEMM: U[b][p][x] = inv[x] * sum_c A[b][p][c]*S[b][c][x] ----------------
// block: 256 thr (4 waves), N-tile 64 cols; wave w: m=64 (4 m-tiles) x n=16 (subtile w)
template <int H>
__device__ __forceinline__ void gemm_body(const float* __restrict__ S, const short* __restrict__ A,
                                          short* __restrict__ U, int bid,
                                          short* __restrict__ Bb, float* __restrict__ red,
                                          float* __restrict__ invs) {
    constexpr int N = H * H;
    constexpr int NBLK = N / 64;
    int b = bid / NBLK;
    int n0 = (bid % NBLK) * 64;
    int t = threadIdx.x;
    int w = t >> 6, l = t & 63, g = l >> 4, ln = l & 15;
    int cg = t >> 4;               // 0..15 staging row group
    int nc = t & 15;               // 4-col chunk
    const float* Sb = S + (size_t)b * CH * N + n0;
    const short* Ab = A + (size_t)b * 64 * 320;
    f32x4 acc[4];
#pragma unroll
    for (int i = 0; i < 4; ++i) acc[i] = (f32x4){0.f, 0.f, 0.f, 0.f};
    float ssq[4] = {0.f, 0.f, 0.f, 0.f};

    for (int kk = 0; kk < 320; kk += 32) {
        __syncthreads();           // protect Bb reuse
#pragma unroll
        for (int i = 0; i < 2; ++i) {
            int c = cg + 16 * i;
            float4 v = *(const float4*)(Sb + (size_t)(kk + c) * N + nc * 4);
            ssq[0] = fmaf(v.x, v.x, ssq[0]);
            ssq[1] = fmaf(v.y, v.y, ssq[1]);
            ssq[2] = fmaf(v.z, v.z, ssq[2]);
            ssq[3] = fmaf(v.w, v.w, ssq[3]);
            shortx4 h;
            h.x = (short)f2bf(v.x); h.y = (short)f2bf(v.y);
            h.z = (short)f2bf(v.z); h.w = (short)f2bf(v.w);
            *(shortx4*)(Bb + c * 76 + nc * 4) = h;   // [k][n] pad-76 (2-way max on rd/wr)
        }
        __syncthreads();
        bf16x8 af[4];
#pragma unroll
        for (int mt = 0; mt < 4; ++mt)             // A frags direct from global (L2-resident)
            af[mt] = *(const bf16x8*)(Ab + (mt * 16 + ln) * 320 + kk + 8 * g);
        bf16x8 bfr;
#pragma unroll
        for (int j = 0; j < 8; ++j) bfr[j] = Bb[(8 * g + j) * 76 + 16 * w + ln];
#pragma unroll
        for (int mt = 0; mt < 4; ++mt)
            acc[mt] = __builtin_amdgcn_mfma_f32_16x16x32_bf16(af[mt], bfr, acc[mt], 0, 0, 0);
    }
    // per-column inverse norms (search L2-normalization applied on columns of U)
    red[cg * 64 + nc * 4 + 0] = ssq[0];
    red[cg * 64 + nc * 4 + 1] = ssq[1];
    red[cg * 64 + nc * 4 + 2] = ssq[2];
    red[cg * 64 + nc * 4 + 3] = ssq[3];
    __syncthreads();
    if (t < 64) {
        float s = 0.0f;
#pragma unroll
        for (int i = 0; i < 16; ++i) s += red[i * 64 + t];
        invs[t] = 1.0f / fmaxf(sqrtf(s), 1e-12f);
    }
    __syncthreads();
    float iv = invs[16 * w + ln];
#pragma unroll
    for (int mt = 0; mt < 4; ++mt) {
#pragma unroll
        for (int r = 0; r < 4; ++r) {              // C/D: col=lane&15, row=(lane>>4)*4+reg
            int p = mt * 16 + 4 * g + r;
            U[(size_t)(b * 64 + p) * N + n0 + 16 * w + ln] = (short)f2bf(acc[mt][r] * iv);
        }
    }
}

__global__ __launch_bounds__(256) void gemm_kernel(const float* __restrict__ sp3,
        const float* __restrict__ sp4, const float* __restrict__ sp5,
        const short* __restrict__ abf, short* __restrict__ u) {
    __shared__ short Bb[32 * 76];
    __shared__ float red[16 * 64];
    __shared__ float invs[64];
    int bid = blockIdx.x;
    if (bid < 1024)      gemm_body<64>(sp3, abf,          u + UB3, bid,        Bb, red, invs);
    else if (bid < 1280) gemm_body<32>(sp4, abf + 327680, u + UB4, bid - 1024, Bb, red, invs);
    else                 gemm_body<16>(sp5, abf + 655360, u + UB5, bid - 1280, Bb, red, invs);
}

// ---------------- 5) combine: out[oh][ow] = sum_p U[p][(oh+kh)*H + ow+kw] ----------------
__global__ __launch_bounds__(256) void combine_kernel(const short* __restrict__ U,
                                                      float* __restrict__ out) {
    int tid = blockIdx.x * 256 + threadIdx.x;
    if (tid < 51984) {
        int b = tid / 3249, r = tid % 3249;
        int oh = r / 57, ow = r % 57;
        const short* u = U + UB3 + ((size_t)b * 64) * 4096 + oh * 64 + ow;
        float s = 0.0f;
#pragma unroll
        for (int kh = 0; kh < 8; ++kh)
#pragma unroll
            for (int kw = 0; kw < 8; ++kw)
                s += bf2f((unsigned short)u[(size_t)(kh * 8 + kw) * 4096 + kh * 64 + kw]);
        out[tid] = s;
    } else if (tid < 61984) {
        int x = tid - 51984;
        int b = x / 625, r = x % 625;
        int oh = r / 25, ow = r % 25;
        const short* u = U + UB4 + ((size_t)b * 64) * 1024 + oh * 32 + ow;
        float s = 0.0f;
#pragma unroll
        for (int kh = 0; kh < 8; ++kh)
#pragma unroll
            for (int kw = 0; kw < 8; ++kw)
                s += bf2f((unsigned short)u[(size_t)(kh * 8 + kw) * 1024 + kh * 32 + kw]);
        out[tid] = s;
    } else if (tid < 63280) {
        int x = tid - 61984;
        int b = x / 81, r = x % 81;
        int oh = r / 9, ow = r % 9;
        const short* u = U + UB5 + ((size_t)b * 64) * 256 + oh * 16 + ow;
        float s = 0.0f;
#pragma unroll
        for (int kh = 0; kh < 8; ++kh)
#pragma unroll
            for (int kw = 0; kw < 8; ++kw)
                s += bf2f((unsigned short)u[(size_t)(kh * 8 + kw) * 256 + kh * 16 + kw]);
        out[tid] = s;
    }
}

extern "C" void kernel_launch(void* const* d_in, const int* in_sizes, int n_in,
                              void* d_out, int out_size, void* d_ws, size_t ws_size,
                              hipStream_t stream) {
    const float* t0p3 = (const float*)d_in[0];
    const float* t0p4 = (const float*)d_in[1];
    const float* t0p5 = (const float*)d_in[2];
    const float* t1p3 = (const float*)d_in[3];
    const float* t1p4 = (const float*)d_in[4];
    const float* t1p5 = (const float*)d_in[5];
    const float* t2p3 = (const float*)d_in[6];
    const float* t2p4 = (const float*)d_in[7];
    const float* t2p5 = (const float*)d_in[8];
    const float* sp3  = (const float*)d_in[9];
    const float* sp4  = (const float*)d_in[10];
    const float* sp5  = (const float*)d_in[11];
    const float* f3w1 = (const float*)d_in[12];
    const float* f3b1 = (const float*)d_in[13];
    const float* f3w2 = (const float*)d_in[14];
    const float* f3b2 = (const float*)d_in[15];
    const float* f4w1 = (const float*)d_in[16];
    const float* f4b1 = (const float*)d_in[17];
    const float* f4w2 = (const float*)d_in[18];
    const float* f4b2 = (const float*)d_in[19];
    const float* f5w1 = (const float*)d_in[20];
    const float* f5b1 = (const float*)d_in[21];
    const float* f5w2 = (const float*)d_in[22];
    const float* f5b2 = (const float*)d_in[23];

    float* ws = (float*)d_ws;
    short* abf = (short*)(ws + WS_ABF);
    short* ubuf = (short*)ws;

    prep_kernel<<<11520, 256, 0, stream>>>(t0p3, t1p3, t2p3, t0p4, t1p4, t2p4,
                                           t0p5, t1p5, t2p5,
                                           ws + WS_POOL3, ws + WS_POOL4, ws + WS_MEANS);
    weights_kernel<<<48, 256, 0, stream>>>(ws + WS_MEANS,
                                           f3w1, f3b1, f3w2, f3b2,
                                           f4w1, f4b1, f4w2, f4b2,
                                           f5w1, f5b1, f5w2, f5b2, ws + WS_AW);
    fuse_kernel<<<3840, 256, 0, stream>>>(ws + WS_POOL3, ws + WS_POOL3 + PLSZ, ws + WS_POOL3 + 2 * PLSZ,
                                          ws + WS_POOL4, ws + WS_POOL4 + PLSZ, ws + WS_POOL4 + 2 * PLSZ,
                                          t0p5, t1p5, t2p5,
                                          ws + WS_AW, ws + WS_TF, ws + WS_PART);
    atrans_kernel<<<48, 256, 0, stream>>>(ws + WS_TF, ws + WS_PART, abf);
    gemm_kernel<<<1344, 256, 0, stream>>>(sp3, sp4, sp5, abf, ubuf);
    combine_kernel<<<248, 256, 0, stream>>>(ubuf, (float*)d_out);
}

// Round 5
// 89.381 us; speedup vs baseline: 4.3410x; 1.0860x over previous
//
#include <hip/hip_runtime.h>
#include <math.h>

#define BATCH 16
#define CH 320

typedef __attribute__((ext_vector_type(8))) short bf16x8;
typedef __attribute__((ext_vector_type(4))) float f32x4;

union FragU { bf16x8 f; unsigned long long u[2]; };

// ---------------- workspace layout (floats) ----------------
static constexpr size_t PLSZ     = (size_t)BATCH * CH * 64;      // 327680
static constexpr size_t WS_POOL3 = 0;                            // 3*PLSZ (U overlaps later)
static constexpr size_t WS_POOL4 = 3 * PLSZ;
static constexpr size_t WS_TF    = 6 * PLSZ;
static constexpr size_t WS_MEANS = 9 * PLSZ;                     // 2949120
static constexpr size_t WS_AW    = WS_MEANS + 9 * BATCH * CH;    // +46080
static constexpr size_t WS_PART  = WS_AW + 144;
static constexpr size_t WS_ABF   = WS_PART + 3 * BATCH * 80 * 64; // bf16 A, 983040 shorts
// V buffers (bf16 shorts) overlap POOL3/POOL4/TF (dead by GEMM time). Layout [b][x][64p].
static constexpr size_t UB3 = 0;
static constexpr size_t UB4 = (size_t)BATCH * 4096 * 64;         // 4194304
static constexpr size_t UB5 = UB4 + (size_t)BATCH * 1024 * 64;   // 5242880

__device__ __forceinline__ float bf2f(unsigned short u) {
    union { unsigned int i; float f; } x; x.i = ((unsigned int)u) << 16; return x.f;
}
__device__ __forceinline__ unsigned short f2bf(float f) {
    union { float f; unsigned int i; } x; x.f = f;
    return (unsigned short)((x.i + 0x7FFFu + ((x.i >> 16) & 1u)) >> 16);
}
__device__ __forceinline__ unsigned cvtpk(float lo, float hi) {
    unsigned r;
    asm("v_cvt_pk_bf16_f32 %0, %1, %2" : "=v"(r) : "v"(lo), "v"(hi));
    return r;
}

// ---------------- 1) fused pool(p3)+pool(p4)+mean(p5) ----------------
template <int HW, int KK>
__device__ __forceinline__ void pool_body(int idx, const float* __restrict__ a0,
                                          const float* __restrict__ a1, const float* __restrict__ a2,
                                          float* __restrict__ dst, float* __restrict__ means, int lane) {
    constexpr int NPL = BATCH * CH * 64;
    int tmpl = idx / NPL;
    int r = idx % NPL;
    const float* src = (tmpl == 0) ? a0 : ((tmpl == 1) ? a1 : a2);
    int bc = r >> 6;
    int pos = r & 63;
    int oh = pos >> 3, ow = pos & 7;
    const float* base = src + (size_t)bc * HW * HW;
    float s = 0.0f;
    if constexpr (KK == 4) {
#pragma unroll
        for (int i = 0; i < 4; ++i) {
            float4 v = *(const float4*)(base + (oh * 4 + i) * HW + ow * 4);
            s += v.x + v.y + v.z + v.w;
        }
    } else {
#pragma unroll
        for (int i = 0; i < 2; ++i) {
            float2 v = *(const float2*)(base + (oh * 2 + i) * HW + ow * 2);
            s += v.x + v.y;
        }
    }
    s *= (1.0f / (KK * KK));
    dst[idx] = s;
    float m = s;
#pragma unroll
    for (int o = 32; o; o >>= 1) m += __shfl_xor(m, o);
    if (lane == 0) means[tmpl * (BATCH * CH) + bc] = m * (1.0f / 64.0f);
}

__global__ __launch_bounds__(256) void prep_kernel(
    const float* __restrict__ t0p3, const float* __restrict__ t1p3, const float* __restrict__ t2p3,
    const float* __restrict__ t0p4, const float* __restrict__ t1p4, const float* __restrict__ t2p4,
    const float* __restrict__ t0p5, const float* __restrict__ t1p5, const float* __restrict__ t2p5,
    float* __restrict__ pool3, float* __restrict__ pool4, float* __restrict__ means) {
    int bid = blockIdx.x, t = threadIdx.x, lane = t & 63;
    if (bid < 3840) {
        pool_body<32, 4>(bid * 256 + t, t0p3, t1p3, t2p3, pool3, means, lane);
    } else if (bid < 7680) {
        pool_body<16, 2>((bid - 3840) * 256 + t, t0p4, t1p4, t2p4, pool4, means + 3 * BATCH * CH, lane);
    } else {
        int w = ((bid - 7680) * 256 + t) >> 6;
        constexpr int NR = BATCH * CH;
        int tmpl = w / NR, rem = w % NR;
        const float* src = (tmpl == 0) ? t0p5 : ((tmpl == 1) ? t1p5 : t2p5);
        float v = src[(size_t)rem * 64 + lane];
#pragma unroll
        for (int o = 32; o; o >>= 1) v += __shfl_xor(v, o);
        if (lane == 0) means[6 * BATCH * CH + w] = v * (1.0f / 64.0f);
    }
}

// ---------------- 2) fusion weights ----------------
__global__ __launch_bounds__(256) void weights_kernel(const float* __restrict__ means,
        const float* w13, const float* b13, const float* w23, const float* b23,
        const float* w14, const float* b14, const float* w24, const float* b24,
        const float* w15, const float* b15, const float* w25, const float* b25,
        float* __restrict__ a_out) {
    __shared__ float m[3 * CH];
    __shared__ float hv[240];
    __shared__ float sc[3];
    int lvl = blockIdx.x / BATCH;
    int b = blockIdx.x % BATCH;
    int t = threadIdx.x;
    const float* w1 = (lvl == 0) ? w13 : ((lvl == 1) ? w14 : w15);
    const float* b1 = (lvl == 0) ? b13 : ((lvl == 1) ? b14 : b15);
    const float* w2 = (lvl == 0) ? w23 : ((lvl == 1) ? w24 : w25);
    const float* b2 = (lvl == 0) ? b23 : ((lvl == 1) ? b24 : b25);
    const float* mb = means + lvl * (3 * BATCH * CH);
    for (int j = t; j < 3 * CH; j += 256) {
        int i = j / CH, c = j % CH;
        m[j] = mb[i * (BATCH * CH) + b * CH + c];
    }
    __syncthreads();
    if (t < 240) {
        int i = t / 80, jj = t % 80;
        float acc = b1[jj];
#pragma unroll 4
        for (int c = 0; c < CH; ++c) acc = fmaf(m[i * CH + c], w1[c * 80 + jj], acc);
        hv[t] = fmaxf(acc, 0.0f) * w2[jj];
    }
    __syncthreads();
    if (t < 3) {
        float s = b2[0];
#pragma unroll 8
        for (int jj = 0; jj < 80; ++jj) s += hv[t * 80 + jj];
        sc[t] = s;
    }
    __syncthreads();
    if (t == 0) {
        float mx = fmaxf(sc[0], fmaxf(sc[1], sc[2]));
        float e0 = expf(sc[0] - mx), e1 = expf(sc[1] - mx), e2 = expf(sc[2] - mx);
        float inv = 1.0f / (e0 + e1 + e2);
        float* ao = a_out + lvl * 48 + b * 3;
        ao[0] = e0 * inv; ao[1] = e1 * inv; ao[2] = e2 * inv;
    }
}

// ---------------- 3a) fuse templates + partial sum of squares ----------------
__global__ __launch_bounds__(256) void fuse_kernel(
        const float* __restrict__ p30, const float* __restrict__ p31, const float* __restrict__ p32,
        const float* __restrict__ p40, const float* __restrict__ p41, const float* __restrict__ p42,
        const float* __restrict__ p50, const float* __restrict__ p51, const float* __restrict__ p52,
        const float* __restrict__ aw, float* __restrict__ tf, float* __restrict__ partial) {
    __shared__ float red[256];
    int lvl = blockIdx.x / 1280;
    int r = blockIdx.x % 1280;
    int t = threadIdx.x;
    const float* p0 = (lvl == 0) ? p30 : ((lvl == 1) ? p40 : p50);
    const float* p1 = (lvl == 0) ? p31 : ((lvl == 1) ? p41 : p51);
    const float* p2 = (lvl == 0) ? p32 : ((lvl == 1) ? p42 : p52);
    int idx = r * 256 + t;
    int b = r / 80;
    int j = r % 80;
    const float* ab = aw + lvl * 48 + b * 3;
    float a0 = ab[0], a1 = ab[1], a2 = ab[2];
    float v = a0 * p0[idx] + a1 * p1[idx] + a2 * p2[idx];
    tf[(size_t)lvl * PLSZ + idx] = v;
    red[t] = v * v;
    __syncthreads();
    if (t < 64) {
        float s = red[t] + red[t + 64] + red[t + 128] + red[t + 192];
        partial[((size_t)(lvl * BATCH + b) * 80 + j) * 64 + t] = s;
    }
}

// ---------------- 3b) finalize sinv + transpose + scale -> bf16 A [lvl][b][p][c] ----------------
__global__ __launch_bounds__(256) void atrans_kernel(const float* __restrict__ tf,
        const float* __restrict__ part, short* __restrict__ abf) {
    __shared__ float lds[64 * 68];
    __shared__ float red2[4 * 64];
    __shared__ float sv[64];
    int lvl = blockIdx.x >> 4;
    int b = blockIdx.x & 15;
    int t = threadIdx.x;
    {
        const float* p = part + ((size_t)(lvl * BATCH + b) * 80) * 64 + (t & 63);
        int jg = t >> 6;
        float s = 0.0f;
        for (int j = jg * 20; j < jg * 20 + 20; ++j) s += p[j * 64];
        red2[jg * 64 + (t & 63)] = s;
    }
    __syncthreads();
    if (t < 64) {
        float s = red2[t] + red2[64 + t] + red2[128 + t] + red2[192 + t];
        sv[t] = 1.0f / fmaxf(sqrtf(s), 1e-12f);
    }
    __syncthreads();
    const float* tb = tf + (size_t)lvl * PLSZ + (size_t)b * (CH * 64);
    short* ab = abf + ((size_t)(lvl * BATCH + b) * 64) * 320;
    for (int c0 = 0; c0 < 320; c0 += 64) {
        __syncthreads();
#pragma unroll
        for (int i = 0; i < 4; ++i) {
            int c = (t >> 4) + 16 * i;
            int p4 = (t & 15) * 4;
            *(float4*)(lds + c * 68 + p4) = *(const float4*)(tb + (size_t)(c0 + c) * 64 + p4);
        }
        __syncthreads();
        int p = t >> 2;
        int cs = (t & 3) * 16;
        float s_p = sv[p];
        bf16x8 o0, o1;
#pragma unroll
        for (int u = 0; u < 8; ++u) o0[u] = (short)f2bf(lds[(cs + u) * 68 + p] * s_p);
#pragma unroll
        for (int u = 0; u < 8; ++u) o1[u] = (short)f2bf(lds[(cs + 8 + u) * 68 + p] * s_p);
        *(bf16x8*)(ab + (size_t)p * 320 + c0 + cs) = o0;
        *(bf16x8*)(ab + (size_t)p * 320 + c0 + cs + 8) = o1;
    }
}

// ---------------- 4) swapped-operand MFMA GEMM ----------------
// V[b][x][p] = inv[x] * sum_c T[p][c] * S[b][c][x]   (A-op = S from LDS via tr-reads, B-op = T regs)
// LDS stage map: elem E(c,x) = ((x>>4)*8 + (c>>2))*64 + (c&3)*16 + (x&15)  (4x16 subtiles)
// tr-read semantics (m156/m162-derived): lane byte addr A, a=A/2: reads elems
//   (a&~63) + ((a&63)>>2) + 16j  -> column (a&63)>>2 of subtile a>>6.
// So lane(ln,g), m-tile mt: base = g*256 + ln*8, offsets mt*1024 + {0,128} give
//   A-frag elems S[c = 8g + {j, 4+j}][x = 16mt + ln]  as required.
template <int H>
__device__ __forceinline__ void gemm_body(const float* __restrict__ S, const short* __restrict__ T,
                                          short* __restrict__ V, int bid,
                                          unsigned short* St, float* red, float* invs) {
    constexpr int N = H * H;
    constexpr int XB = N / 64;
    int b = bid / XB;
    int x0b = (bid % XB) * 64;
    int t = threadIdx.x;
    int w = t >> 6, l = t & 63, g = l >> 4, ln = l & 15;
    int cg = t >> 4;            // 0..15 staging c-group
    int x0 = (t & 15) * 4;      // staging x base

    const float* Sb = S + (size_t)b * CH * N + x0b;
    const short* Tp = T + ((size_t)b * 64 + 16 * w + ln) * 320 + 8 * g;

    f32x4 acc[4];
#pragma unroll
    for (int i = 0; i < 4; ++i) acc[i] = (f32x4){0.f, 0.f, 0.f, 0.f};
    float ssq[4] = {0.f, 0.f, 0.f, 0.f};

    // per-lane tr-read base: column = ln, subtile pair = 2g (see derivation above)
    unsigned trbase = (unsigned)(size_t)St + (unsigned)(g * 256 + ln * 8);
    // subtiled stage offset: elem = ((x>>4)*8 + (c>>2))*64 + (c&3)*16 + (x&15)
    int e1 = ((x0 >> 4) * 8 + (cg >> 2)) * 64 + (cg & 3) * 16 + (x0 & 15);

    // ---- prologue: stage k-step 0 into buf0 ----
    {
        const float* p = Sb + (size_t)cg * N + x0;
        float4 v1 = *(const float4*)(p);
        float4 v2 = *(const float4*)(p + (size_t)16 * N);
        ssq[0] = fmaf(v1.x, v1.x, fmaf(v2.x, v2.x, ssq[0]));
        ssq[1] = fmaf(v1.y, v1.y, fmaf(v2.y, v2.y, ssq[1]));
        ssq[2] = fmaf(v1.z, v1.z, fmaf(v2.z, v2.z, ssq[2]));
        ssq[3] = fmaf(v1.w, v1.w, fmaf(v2.w, v2.w, ssq[3]));
        *(uint2*)(St + e1)       = (uint2){cvtpk(v1.x, v1.y), cvtpk(v1.z, v1.w)};
        *(uint2*)(St + e1 + 256) = (uint2){cvtpk(v2.x, v2.y), cvtpk(v2.z, v2.w)};
    }
    bf16x8 tcur = *(const bf16x8*)(Tp);
    __syncthreads();

#define TRRD2(FR, OFF) \
    asm volatile("ds_read_b64_tr_b16 %0, %2 offset:%c3\n\tds_read_b64_tr_b16 %1, %2 offset:%c4" \
                 : "=v"((FR).u[0]), "=v"((FR).u[1]) : "v"(trbase), "i"(OFF), "i"((OFF) + 128));

#define GSTEP(BUF, S_) { \
    int kn = 32 * ((S_) + 1); \
    bool dost = kn < 320; \
    int kl = dost ? kn : 288; \
    const float* p_ = Sb + (size_t)(kl + cg) * N + x0; \
    float4 v1 = *(const float4*)(p_); \
    float4 v2 = *(const float4*)(p_ + (size_t)16 * N); \
    bf16x8 tnx = *(const bf16x8*)(Tp + kl); \
    FragU fr0, fr1, fr2, fr3; \
    TRRD2(fr0, (BUF) * 4096 + 0) \
    TRRD2(fr1, (BUF) * 4096 + 1024) \
    TRRD2(fr2, (BUF) * 4096 + 2048) \
    TRRD2(fr3, (BUF) * 4096 + 3072) \
    asm volatile("s_waitcnt lgkmcnt(0)" ::: "memory"); \
    __builtin_amdgcn_sched_barrier(0); \
    acc[0] = __builtin_amdgcn_mfma_f32_16x16x32_bf16(fr0.f, tcur, acc[0], 0, 0, 0); \
    acc[1] = __builtin_amdgcn_mfma_f32_16x16x32_bf16(fr1.f, tcur, acc[1], 0, 0, 0); \
    acc[2] = __builtin_amdgcn_mfma_f32_16x16x32_bf16(fr2.f, tcur, acc[2], 0, 0, 0); \
    acc[3] = __builtin_amdgcn_mfma_f32_16x16x32_bf16(fr3.f, tcur, acc[3], 0, 0, 0); \
    if (dost) { \
        ssq[0] = fmaf(v1.x, v1.x, fmaf(v2.x, v2.x, ssq[0])); \
        ssq[1] = fmaf(v1.y, v1.y, fmaf(v2.y, v2.y, ssq[1])); \
        ssq[2] = fmaf(v1.z, v1.z, fmaf(v2.z, v2.z, ssq[2])); \
        ssq[3] = fmaf(v1.w, v1.w, fmaf(v2.w, v2.w, ssq[3])); \
        unsigned short* d_ = St + (((BUF) ^ 1) * 2048) + e1; \
        *(uint2*)(d_)       = (uint2){cvtpk(v1.x, v1.y), cvtpk(v1.z, v1.w)}; \
        *(uint2*)(d_ + 256) = (uint2){cvtpk(v2.x, v2.y), cvtpk(v2.z, v2.w)}; \
    } \
    tcur = tnx; \
    __syncthreads(); }

    for (int s = 0; s < 10; s += 2) {
        GSTEP(0, s)
        GSTEP(1, s + 1)
    }
#undef GSTEP
#undef TRRD2

    // ---- per-x inverse search norms ----
    *(f32x4*)(red + cg * 64 + x0) = (f32x4){ssq[0], ssq[1], ssq[2], ssq[3]};
    __syncthreads();
    if (t < 64) {
        float s = 0.0f;
#pragma unroll
        for (int i = 0; i < 16; ++i) s += red[i * 64 + t];
        invs[t] = 1.0f / fmaxf(sqrtf(s), 1e-12f);
    }
    __syncthreads();

    short* Vb = V + ((size_t)b * N + x0b) * 64 + 16 * w + ln;
#pragma unroll
    for (int mt = 0; mt < 4; ++mt) {
        f32x4 iv = *(f32x4*)(invs + mt * 16 + 4 * g);
#pragma unroll
        for (int r = 0; r < 4; ++r)
            Vb[(size_t)(mt * 16 + 4 * g + r) * 64] = (short)f2bf(acc[mt][r] * iv[r]);
    }
}

__global__ __launch_bounds__(256) void gemm_kernel(const float* __restrict__ sp3,
        const float* __restrict__ sp4, const float* __restrict__ sp5,
        const short* __restrict__ abf, short* __restrict__ u) {
    __shared__ unsigned short St[2 * 2048];
    __shared__ float red[16 * 64];
    __shared__ float invs[64];
    int bid = blockIdx.x;
    if (bid < 1024)      gemm_body<64>(sp3, abf,          u + UB3, bid,        St, red, invs);
    else if (bid < 1280) gemm_body<32>(sp4, abf + 327680, u + UB4, bid - 1024, St, red, invs);
    else                 gemm_body<16>(sp5, abf + 655360, u + UB5, bid - 1280, St, red, invs);
}

// ---------------- 5) combine: out[oh][ow] = sum_{kh,kw} V[(oh+kh)*H+ow+kw][kh*8+kw] ----------------
__global__ __launch_bounds__(256) void combine_kernel(const short* __restrict__ U,
                                                      float* __restrict__ out) {
    int tid = blockIdx.x * 256 + threadIdx.x;
    if (tid < 51984) {
        int b = tid / 3249, r = tid % 3249;
        int oh = r / 57, ow = r % 57;
        const short* u = U + UB3 + ((size_t)b * 4096 + oh * 64 + ow) * 64;
        float s = 0.0f;
#pragma unroll
        for (int kh = 0; kh < 8; ++kh)
#pragma unroll
            for (int kw = 0; kw < 8; ++kw)
                s += bf2f((unsigned short)u[(kh * 64 + kw) * 64 + kh * 8 + kw]);
        out[tid] = s;
    } else if (tid < 61984) {
        int x = tid - 51984;
        int b = x / 625, r = x % 625;
        int oh = r / 25, ow = r % 25;
        const short* u = U + UB4 + ((size_t)b * 1024 + oh * 32 + ow) * 64;
        float s = 0.0f;
#pragma unroll
        for (int kh = 0; kh < 8; ++kh)
#pragma unroll
            for (int kw = 0; kw < 8; ++kw)
                s += bf2f((unsigned short)u[(kh * 32 + kw) * 64 + kh * 8 + kw]);
        out[tid] = s;
    } else if (tid < 63280) {
        int x = tid - 61984;
        int b = x / 81, r = x % 81;
        int oh = r / 9, ow = r % 9;
        const short* u = U + UB5 + ((size_t)b * 256 + oh * 16 + ow) * 64;
        float s = 0.0f;
#pragma unroll
        for (int kh = 0; kh < 8; ++kh)
#pragma unroll
            for (int kw = 0; kw < 8; ++kw)
                s += bf2f((unsigned short)u[(kh * 16 + kw) * 64 + kh * 8 + kw]);
        out[tid] = s;
    }
}

extern "C" void kernel_launch(void* const* d_in, const int* in_sizes, int n_in,
                              void* d_out, int out_size, void* d_ws, size_t ws_size,
                              hipStream_t stream) {
    const float* t0p3 = (const float*)d_in[0];
    const float* t0p4 = (const float*)d_in[1];
    const float* t0p5 = (const float*)d_in[2];
    const float* t1p3 = (const float*)d_in[3];
    const float* t1p4 = (const float*)d_in[4];
    const float* t1p5 = (const float*)d_in[5];
    const float* t2p3 = (const float*)d_in[6];
    const float* t2p4 = (const float*)d_in[7];
    const float* t2p5 = (const float*)d_in[8];
    const float* sp3  = (const float*)d_in[9];
    const float* sp4  = (const float*)d_in[10];
    const float* sp5  = (const float*)d_in[11];
    const float* f3w1 = (const float*)d_in[12];
    const float* f3b1 = (const float*)d_in[13];
    const float* f3w2 = (const float*)d_in[14];
    const float* f3b2 = (const float*)d_in[15];
    const float* f4w1 = (const float*)d_in[16];
    const float* f4b1 = (const float*)d_in[17];
    const float* f4w2 = (const float*)d_in[18];
    const float* f4b2 = (const float*)d_in[19];
    const float* f5w1 = (const float*)d_in[20];
    const float* f5b1 = (const float*)d_in[21];
    const float* f5w2 = (const float*)d_in[22];
    const float* f5b2 = (const float*)d_in[23];

    float* ws = (float*)d_ws;
    short* abf = (short*)(ws + WS_ABF);
    short* ubuf = (short*)ws;

    prep_kernel<<<11520, 256, 0, stream>>>(t0p3, t1p3, t2p3, t0p4, t1p4, t2p4,
                                           t0p5, t1p5, t2p5,
                                           ws + WS_POOL3, ws + WS_POOL4, ws + WS_MEANS);
    weights_kernel<<<48, 256, 0, stream>>>(ws + WS_MEANS,
                                           f3w1, f3b1, f3w2, f3b2,
                                           f4w1, f4b1, f4w2, f4b2,
                                           f5w1, f5b1, f5w2, f5b2, ws + WS_AW);
    fuse_kernel<<<3840, 256, 0, stream>>>(ws + WS_POOL3, ws + WS_POOL3 + PLSZ, ws + WS_POOL3 + 2 * PLSZ,
                                          ws + WS_POOL4, ws + WS_POOL4 + PLSZ, ws + WS_POOL4 + 2 * PLSZ,
                                          t0p5, t1p5, t2p5,
                                          ws + WS_AW, ws + WS_TF, ws + WS_PART);
    atrans_kernel<<<48, 256, 0, stream>>>(ws + WS_TF, ws + WS_PART, abf);
    gemm_kernel<<<1344, 256, 0, stream>>>(sp3, sp4, sp5, abf, ubuf);
    combine_kernel<<<248, 256, 0, stream>>>(ubuf, (float*)d_out);
}